// Round 6
// baseline (1070.822 us; speedup 1.0000x reference)
//
#include <hip/hip_runtime.h>
#include <math.h>

#define CDIM 128
#define EDIM 512
#define BLK 256
#define MT 64                 // vectors per block
#define ECH 64                // embeddings per staged chunk
#define NCH 8
#define NVEC 262144           // 8*32*32*32
#define SPATIAL 32768
#define QELEMS 33554432LL
#define TIE_T 2.5e-4f         // covers fp16 2-pass worst-case score error (<=1.2e-4/score)

typedef _Float16 f16x8 __attribute__((ext_vector_type(8)));
typedef float    f32x4 __attribute__((ext_vector_type(4)));

struct WS {
  float  wnh[EDIM];                 // 0.5*||e||^2
  int    counts[EDIM];
  double lossAcc;
  double _pad;
  unsigned short wph[EDIM * CDIM];  // w fp16 bits, MFMA A-fragment order
};

__device__ inline void ins3(float v, int ix, float& m1, float& m2, float& m3,
                            int& j1, int& j2) {
  bool q1 = (v < m1) || (v == m1 && ix < j1);
  bool q2 = (v < m2) || (v == m2 && ix < j2);
  if (q1)      { m3 = m2; m2 = m1; j2 = j1; m1 = v; j1 = ix; }
  else if (q2) { m3 = m2; m2 = v; j2 = ix; }
  else if (v < m3) { m3 = v; }
}

// ---- pre-pass (64 blocks x 256 thr): half norms, zero accumulators, w -> fp16 fragment order
// half index: (e>>6)*8192 + ((et*4+kt)*64 + l)*8 + j, et=(e>>4)&3, kt=k>>5,
// l=((k>>3)&3)*16+(e&15), j=k&7  -> lane-linear 16B fragments
__global__ __launch_bounds__(256) void vq_pre(const float* __restrict__ wt,
                                              WS* __restrict__ ws, int buildWP) {
  const int tid = threadIdx.x, bid = blockIdx.x;
  const int e = bid * 8 + (tid >> 5);
  const int k0 = (tid & 31) * 4;
  float4 F = *(const float4*)(wt + (size_t)e * CDIM + k0);
  float nrm = F.x * F.x + F.y * F.y + F.z * F.z + F.w * F.w;
#pragma unroll
  for (int off = 1; off < 32; off <<= 1) nrm += __shfl_xor(nrm, off);
  if ((tid & 31) == 0) ws->wnh[e] = 0.5f * nrm;
  if (tid < 8) ws->counts[bid * 8 + tid] = 0;
  if (bid == 0 && tid == 0) ws->lossAcc = 0.0;
  if (buildWP) {
    union { _Float16 h[4]; uint2 u; } P;
    P.h[0] = (_Float16)F.x; P.h[1] = (_Float16)F.y;
    P.h[2] = (_Float16)F.z; P.h[3] = (_Float16)F.w;
    size_t idx = (size_t)(e >> 6) * 8192 +
                 (size_t)(((((e >> 4) & 3) * 4 + (k0 >> 5)) * 64) +
                          ((k0 >> 3) & 3) * 16 + (e & 15)) * 8 + (k0 & 7);
    *(uint2*)&ws->wph[idx] = P.u;
  }
}

// x LDS layout (per hi/lo array, fp16): elem(m,k) = (k>>3)*512 + (m>>4)*128 + fm*8 + (k&7),
//   fm = (m&15)^((m&15)>>2)  (verified swizzle from r2/r4)
template <bool USEWP>
__global__ __launch_bounds__(BLK, 4) void vq_main(const float* __restrict__ in,
                                                  const float* __restrict__ wt,
                                                  WS* __restrict__ ws,
                                                  float* __restrict__ out_q,
                                                  float* __restrict__ enc) {
  __shared__ __align__(16) char uni[32768];   // [xh 16K | xl 16K] -> [wbuf 16K | tie scratch]
  __shared__ int    hist[EDIM];
  __shared__ int    sIdx[MT];
  __shared__ double lredw[4];

  const int tid = threadIdx.x;
  const int lane = tid & 63, wv = tid >> 6;
  const int col = lane & 15, g = lane >> 4;
  const int fcol = col ^ (col >> 2);
  const int n0 = blockIdx.x * MT;
  const int b  = n0 >> 15;
  const int s0 = n0 & (SPATIAL - 1);
  const size_t ibase = (size_t)b * CDIM * SPATIAL;

  for (int e = tid; e < EDIM; e += BLK) hist[e] = 0;

  uint4 G[4];
  auto loadG = [&](int ch) {
    if (USEWP) {
      const uint4* p = (const uint4*)ws->wph + (size_t)ch * 1024;
#pragma unroll
      for (int i = 0; i < 4; ++i) G[i] = p[i * BLK + tid];
    } else {
#pragma unroll
      for (int i = 0; i < 4; ++i) {
        int q = i * BLK + tid;                 // 0..1023
        int e = ch * 64 + (q >> 8) * 16 + (q & 15);
        int kb = ((q >> 6) & 3) * 32 + ((q >> 4) & 3) * 8;
        float4 A = *(const float4*)(wt + (size_t)e * CDIM + kb);
        float4 Bv = *(const float4*)(wt + (size_t)e * CDIM + kb + 4);
        union { _Float16 h[8]; uint4 u; } P;
        P.h[0]=(_Float16)A.x; P.h[1]=(_Float16)A.y; P.h[2]=(_Float16)A.z; P.h[3]=(_Float16)A.w;
        P.h[4]=(_Float16)Bv.x; P.h[5]=(_Float16)Bv.y; P.h[6]=(_Float16)Bv.z; P.h[7]=(_Float16)Bv.w;
        G[i] = P.u;
      }
    }
  };

  // ---- stage x: fp32 -> fp16 hi/lo into swizzled LDS (freed after hoist)
  {
    const int mq = tid & 15, cg = tid >> 4;
    const int m0 = mq * 4, c0 = cg * 8;
    float4 F[8];
#pragma unroll
    for (int i = 0; i < 8; ++i)
      F[i] = *(const float4*)(in + ibase + (size_t)(c0 + i) * SPATIAL + s0 + m0);
    loadG(0);                                  // prefetch w chunk 0 under conversion
    _Float16* xh = (_Float16*)uni;
    _Float16* xl = (_Float16*)(uni + 16384);
#pragma unroll
    for (int mi = 0; mi < 4; ++mi) {
      const int m = m0 + mi;
      union { _Float16 h[8]; uint4 u; } H, L;
#pragma unroll
      for (int p = 0; p < 8; ++p) {
        float f = ((const float*)&F[p])[mi];
        _Float16 hh = (_Float16)f;
        H.h[p] = hh;
        L.h[p] = (_Float16)(f - (float)hh);
      }
      const int fm = (m & 15) ^ ((m & 15) >> 2);
      const int elem = cg * 512 + (m >> 4) * 128 + fm * 8;
      *(uint4*)&xh[elem] = H.u;
      *(uint4*)&xl[elem] = L.u;
    }
  }
  __syncthreads();

  // ---- hoist this wave's x fragments (m = wv*16+col, all 128 k) into registers
  f16x8 bh[4], bl[4];
  {
    const _Float16* xh = (const _Float16*)uni;
    const _Float16* xl = (const _Float16*)(uni + 16384);
#pragma unroll
    for (int kt = 0; kt < 4; ++kt) {
      const int eo = (kt * 4 + g) * 512 + wv * 128 + fcol * 8;
      bh[kt] = *(const f16x8*)(xh + eo);
      bl[kt] = *(const f16x8*)(xl + eo);
    }
  }

  float b1 = 1e30f, b2 = 1e30f, b3 = 1e30f;
  int i1v = 0, i2v = 0;

  // ---- main loop: single 16KB w buffer, register prefetch, counted-wait barrier
  for (int ch = 0; ch < NCH; ++ch) {
    __syncthreads();                           // prev chunk's readers done (covers hoist at ch=0)
#pragma unroll
    for (int i = 0; i < 4; ++i)
      *(uint4*)(uni + (size_t)(i * BLK + tid) * 16) = G[i];
    if (ch + 1 < NCH) loadG(ch + 1);           // global loads stay in flight across raw barrier
    asm volatile("s_waitcnt lgkmcnt(0)" ::: "memory");
    __builtin_amdgcn_sched_barrier(0);         // rule #18: pin reads after the waitcnt
    __builtin_amdgcn_s_barrier();

    const _Float16* wb = (const _Float16*)uni;
#pragma unroll
    for (int et = 0; et < 4; ++et) {
      f16x8 ah[4];
#pragma unroll
      for (int kt = 0; kt < 4; ++kt)
        ah[kt] = *(const f16x8*)(wb + ((et * 4 + kt) * 64 + lane) * 8);
      f32x4 a = {0.f, 0.f, 0.f, 0.f};
#pragma unroll
      for (int kt = 0; kt < 4; ++kt) {
        a = __builtin_amdgcn_mfma_f32_16x16x32_f16(ah[kt], bh[kt], a, 0, 0, 0);
        a = __builtin_amdgcn_mfma_f32_16x16x32_f16(ah[kt], bl[kt], a, 0, 0, 0);
      }
      const int e0 = ch * ECH + et * 16 + g * 4;
      const float4 wn = *(const float4*)(ws->wnh + e0);
#pragma unroll
      for (int r = 0; r < 4; ++r) {
        float sc = ((const float*)&wn)[r] - a[r];
        ins3(sc, e0 + r, b1, b2, b3, i1v, i2v);
      }
    }
  }

  // ---- intra-wave butterfly over g (disjoint e-sets) -> lanes of same col hold merged top-3
#pragma unroll
  for (int sh = 0; sh < 2; ++sh) {
    const int off = 16 << sh;
    float p1 = __shfl_xor(b1, off), p2 = __shfl_xor(b2, off), p3 = __shfl_xor(b3, off);
    int q1 = __shfl_xor(i1v, off), q2 = __shfl_xor(i2v, off);
    ins3(p1, q1, b1, b2, b3, i1v, i2v);
    ins3(p2, q2, b1, b2, b3, i1v, i2v);
    ins3(p3, 0x7fffffff, b1, b2, b3, i1v, i2v);
  }

  // ---- tie handling, per wave (x~ from regs; fp64-on-x~ consistent across paths)
  {
    const bool t2 = (b2 - b1 < TIE_T);
    const bool t3 = (b3 - b1 < TIE_T);
    if (g == 0 && !t2 && !t3) { sIdx[wv * 16 + col] = i1v; atomicAdd(&hist[i1v], 1); }
    unsigned long long mask = __ballot(t2 || t3) & 0xFFFFull;
    float* scr = (float*)(uni + 16384 + wv * 512);
    while (mask) {
      const int bsel = __ffsll((unsigned long long)mask) - 1;
      mask &= mask - 1;
      if (col == bsel) {
#pragma unroll
        for (int kt = 0; kt < 4; ++kt)
#pragma unroll
          for (int j = 0; j < 8; ++j)
            scr[kt * 32 + g * 8 + j] = (float)bh[kt][j] + (float)bl[kt][j];
      }
      asm volatile("s_waitcnt lgkmcnt(0)" ::: "memory");
      __builtin_amdgcn_sched_barrier(0);       // rule #18
      const int j1s = __shfl(i1v, bsel), j2s = __shfl(i2v, bsel);
      const int isfull = __shfl((int)t3, bsel);
      int bi;
      if (isfull) {
        // candidate-parallel exact scan: 8 candidates per lane
        double bd = 1e300; int bj = 0x7fffffff;
        for (int i = 0; i < 8; ++i) {
          const int e = lane * 8 + i;
          const float* w = wt + (size_t)e * CDIM;
          double s = 0.0;
#pragma unroll 4
          for (int c = 0; c < CDIM; ++c) {
            double wd = (double)w[c];
            s = fma(wd, fma(0.5, wd, -(double)scr[c]), s);
          }
          if (s < bd || (s == bd && e < bj)) { bd = s; bj = e; }
        }
#pragma unroll
        for (int off = 32; off > 0; off >>= 1) {
          double od = __shfl_xor(bd, off); int oj = __shfl_xor(bj, off);
          if (od < bd || (od == bd && oj < bj)) { bd = od; bj = oj; }
        }
        bi = bj;
      } else {
        // 2-candidate parallel rescore: lanes<32 -> j1, lanes>=32 -> j2
        const int cand = (lane < 32) ? j1s : j2s;
        const int c0 = (lane & 31) * 4;
        const float* w = wt + (size_t)cand * CDIM;
        double p = 0.0;
#pragma unroll
        for (int cc = 0; cc < 4; ++cc) {
          double wd = (double)w[c0 + cc];
          p = fma(wd, fma(0.5, wd, -(double)scr[c0 + cc]), p);
        }
#pragma unroll
        for (int off = 16; off > 0; off >>= 1) p += __shfl_xor(p, off);
        double s1 = __shfl(p, 0), s2 = __shfl(p, 32);
        bi = (s2 < s1 || (s2 == s1 && j2s < j1s)) ? j2s : j1s;
      }
      if (lane == 0) { sIdx[wv * 16 + bsel] = bi; atomicAdd(&hist[bi], 1); }
    }
  }
  __syncthreads();

  // ---- out_q + loss from register x~ (no global x re-read)
  {
    const int m = wv * 16 + col;
    const int bi = sIdx[m];
    const float* wq = wt + (size_t)bi * CDIM;
    const size_t gbase = ibase + s0 + m;
    float ls = 0.f;
#pragma unroll
    for (int kt = 0; kt < 4; ++kt) {
      const int cb = kt * 32 + g * 8;
      float4 qa = *(const float4*)(wq + cb);
      float4 qb = *(const float4*)(wq + cb + 4);
      float qf[8] = {qa.x, qa.y, qa.z, qa.w, qb.x, qb.y, qb.z, qb.w};
#pragma unroll
      for (int j = 0; j < 8; ++j) {
        float xs = (float)bh[kt][j] + (float)bl[kt][j];
        float d = qf[j] - xs;
        ls = fmaf(d, d, ls);
        __builtin_nontemporal_store(qf[j], out_q + gbase + (size_t)(cb + j) * SPATIAL);
      }
    }
#pragma unroll
    for (int off = 32; off > 0; off >>= 1) ls += __shfl_xor(ls, off);
    if (lane == 0) lredw[wv] = (double)ls;
  }
  __syncthreads();
  if (tid == 0) atomicAdd(&ws->lossAcc, lredw[0] + lredw[1] + lredw[2] + lredw[3]);

  // ---- encodings: 64 one-hot rows, 256 u64 columns (r2/r4-verified writer)
  {
    const size_t r0 = (size_t)blockIdx.x * MT;
    const int c0 = tid * 2;
    unsigned long long* e2 = (unsigned long long*)enc;
    for (int r = 0; r < MT; ++r) {
      int idx = sIdx[r];
      union { float2 f; unsigned long long u; } cvt;
      cvt.f.x = (idx == c0) ? 1.0f : 0.0f;
      cvt.f.y = (idx == c0 + 1) ? 1.0f : 0.0f;
      __builtin_nontemporal_store(cvt.u, e2 + (r0 + (size_t)r) * (EDIM / 2) + tid);
    }
  }

  for (int e = tid; e < EDIM; e += BLK) {
    int v = hist[e];
    if (v) atomicAdd(&ws->counts[e], v);
  }
}

// ---- finalize
__global__ __launch_bounds__(512) void vq_fin(const WS* __restrict__ ws, float* __restrict__ out) {
  __shared__ double red[EDIM];
  int t = threadIdx.x;
  double p = (double)ws->counts[t] * (1.0 / (double)NVEC);
  red[t] = p * log(p + 1e-10);
  __syncthreads();
  for (int off = 256; off > 0; off >>= 1) {
    if (t < off) red[t] += red[t + off];
    __syncthreads();
  }
  if (t == 0) {
    out[0] = (float)(1.25 * ws->lossAcc / (double)QELEMS);
    out[1 + QELEMS] = (float)exp(-red[0]);
  }
}

extern "C" void kernel_launch(void* const* d_in, const int* in_sizes, int n_in,
                              void* d_out, int out_size, void* d_ws, size_t ws_size,
                              hipStream_t stream) {
  const float* in = (const float*)d_in[0];
  const float* wt = (const float*)d_in[1];
  float* out = (float*)d_out;
  WS* ws = (WS*)d_ws;

  float* out_q = out + 1;
  float* enc   = out + 2 + QELEMS;

  const bool useWP = (ws_size >= sizeof(WS));
  vq_pre<<<dim3(64), dim3(256), 0, stream>>>(wt, ws, useWP ? 1 : 0);
  if (useWP)
    vq_main<true><<<dim3(NVEC / MT), dim3(BLK), 0, stream>>>(in, wt, ws, out_q, enc);
  else
    vq_main<false><<<dim3(NVEC / MT), dim3(BLK), 0, stream>>>(in, wt, ws, out_q, enc);
  vq_fin<<<dim3(1), dim3(512), 0, stream>>>(ws, out);
}

// Round 7
// 1069.214 us; speedup vs baseline: 1.0015x; 1.0015x over previous
//
#include <hip/hip_runtime.h>
#include <math.h>

#define CDIM 128
#define EDIM 512
#define BLK 256
#define MT 64                 // vectors per block
#define ECH 64                // embeddings per staged chunk
#define NCH 8
#define NVEC 262144           // 8*32*32*32
#define SPATIAL 32768
#define QELEMS 33554432LL
#define TIE_T 2.5e-4f         // covers fp16 2-pass worst-case score error (<=1.2e-4/score)

typedef _Float16 f16x8 __attribute__((ext_vector_type(8)));
typedef float    f32x4 __attribute__((ext_vector_type(4)));

struct WS {
  float  wnh[EDIM];                 // 0.5*||e||^2
  int    counts[EDIM];
  double lossAcc;
  double _pad;
  unsigned short wph[EDIM * CDIM];  // w fp16 bits, MFMA A-fragment order
};

__device__ inline void ins3(float v, int ix, float& m1, float& m2, float& m3,
                            int& j1, int& j2) {
  bool q1 = (v < m1) || (v == m1 && ix < j1);
  bool q2 = (v < m2) || (v == m2 && ix < j2);
  if (q1)      { m3 = m2; m2 = m1; j2 = j1; m1 = v; j1 = ix; }
  else if (q2) { m3 = m2; m2 = v; j2 = ix; }
  else if (v < m3) { m3 = v; }
}

// ---- pre-pass (64 blocks x 256 thr): half norms, zero accumulators, w -> fp16 fragment order
// half index: (e>>6)*8192 + ((et*4+kt)*64 + l)*8 + j, et=(e>>4)&3, kt=k>>5,
// l=((k>>3)&3)*16+(e&15), j=k&7  -> lane-linear 16B fragments
__global__ __launch_bounds__(256) void vq_pre(const float* __restrict__ wt,
                                              WS* __restrict__ ws, int buildWP) {
  const int tid = threadIdx.x, bid = blockIdx.x;
  const int e = bid * 8 + (tid >> 5);
  const int k0 = (tid & 31) * 4;
  float4 F = *(const float4*)(wt + (size_t)e * CDIM + k0);
  float nrm = F.x * F.x + F.y * F.y + F.z * F.z + F.w * F.w;
#pragma unroll
  for (int off = 1; off < 32; off <<= 1) nrm += __shfl_xor(nrm, off);
  if ((tid & 31) == 0) ws->wnh[e] = 0.5f * nrm;
  if (tid < 8) ws->counts[bid * 8 + tid] = 0;
  if (bid == 0 && tid == 0) ws->lossAcc = 0.0;
  if (buildWP) {
    union { _Float16 h[4]; uint2 u; } P;
    P.h[0] = (_Float16)F.x; P.h[1] = (_Float16)F.y;
    P.h[2] = (_Float16)F.z; P.h[3] = (_Float16)F.w;
    size_t idx = (size_t)(e >> 6) * 8192 +
                 (size_t)(((((e >> 4) & 3) * 4 + (k0 >> 5)) * 64) +
                          ((k0 >> 3) & 3) * 16 + (e & 15)) * 8 + (k0 & 7);
    *(uint2*)&ws->wph[idx] = P.u;
  }
}

// x LDS layout (per hi/lo array, fp16): elem(m,k) = (k>>3)*512 + (m>>4)*128 + fm*8 + (k&7),
//   fm = (m&15)^((m&15)>>2)  (verified swizzle from r2/r4)
template <bool USEWP>
__global__ __launch_bounds__(BLK, 4) void vq_main(const float* __restrict__ in,
                                                  const float* __restrict__ wt,
                                                  WS* __restrict__ ws,
                                                  float* __restrict__ out_q,
                                                  float* __restrict__ enc) {
  __shared__ __align__(16) char uni[32768];   // [xh 16K | xl 16K] -> [wbuf 16K | tie scratch]
  __shared__ int    hist[EDIM];
  __shared__ int    sIdx[MT];
  __shared__ double lredw[4];

  const int tid = threadIdx.x;
  const int lane = tid & 63, wv = tid >> 6;
  const int col = lane & 15, g = lane >> 4;
  const int fcol = col ^ (col >> 2);
  const int n0 = blockIdx.x * MT;
  const int b  = n0 >> 15;
  const int s0 = n0 & (SPATIAL - 1);
  const size_t ibase = (size_t)b * CDIM * SPATIAL;

  for (int e = tid; e < EDIM; e += BLK) hist[e] = 0;

  uint4 G[4];
  auto loadG = [&](int ch) {
    if (USEWP) {
      const uint4* p = (const uint4*)ws->wph + (size_t)ch * 1024;
#pragma unroll
      for (int i = 0; i < 4; ++i) G[i] = p[i * BLK + tid];
    } else {
#pragma unroll
      for (int i = 0; i < 4; ++i) {
        int q = i * BLK + tid;                 // 0..1023
        int e = ch * 64 + (q >> 8) * 16 + (q & 15);
        int kb = ((q >> 6) & 3) * 32 + ((q >> 4) & 3) * 8;
        float4 A = *(const float4*)(wt + (size_t)e * CDIM + kb);
        float4 Bv = *(const float4*)(wt + (size_t)e * CDIM + kb + 4);
        union { _Float16 h[8]; uint4 u; } P;
        P.h[0]=(_Float16)A.x; P.h[1]=(_Float16)A.y; P.h[2]=(_Float16)A.z; P.h[3]=(_Float16)A.w;
        P.h[4]=(_Float16)Bv.x; P.h[5]=(_Float16)Bv.y; P.h[6]=(_Float16)Bv.z; P.h[7]=(_Float16)Bv.w;
        G[i] = P.u;
      }
    }
  };

  // ---- stage x: fp32 -> fp16 hi/lo into swizzled LDS (freed after hoist)
  {
    const int mq = tid & 15, cg = tid >> 4;
    const int m0 = mq * 4, c0 = cg * 8;
    float4 F[8];
#pragma unroll
    for (int i = 0; i < 8; ++i)
      F[i] = *(const float4*)(in + ibase + (size_t)(c0 + i) * SPATIAL + s0 + m0);
    loadG(0);                                  // prefetch w chunk 0 under conversion
    _Float16* xh = (_Float16*)uni;
    _Float16* xl = (_Float16*)(uni + 16384);
#pragma unroll
    for (int mi = 0; mi < 4; ++mi) {
      const int m = m0 + mi;
      union { _Float16 h[8]; uint4 u; } H, L;
#pragma unroll
      for (int p = 0; p < 8; ++p) {
        float f = ((const float*)&F[p])[mi];
        _Float16 hh = (_Float16)f;
        H.h[p] = hh;
        L.h[p] = (_Float16)(f - (float)hh);
      }
      const int fm = (m & 15) ^ ((m & 15) >> 2);
      const int elem = cg * 512 + (m >> 4) * 128 + fm * 8;
      *(uint4*)&xh[elem] = H.u;
      *(uint4*)&xl[elem] = L.u;
    }
  }
  __syncthreads();

  // ---- hoist this wave's x fragments (m = wv*16+col, all 128 k) into registers
  f16x8 bh[4], bl[4];
  {
    const _Float16* xh = (const _Float16*)uni;
    const _Float16* xl = (const _Float16*)(uni + 16384);
#pragma unroll
    for (int kt = 0; kt < 4; ++kt) {
      const int eo = (kt * 4 + g) * 512 + wv * 128 + fcol * 8;
      bh[kt] = *(const f16x8*)(xh + eo);
      bl[kt] = *(const f16x8*)(xl + eo);
    }
  }

  float b1 = 1e30f, b2 = 1e30f, b3 = 1e30f;
  int i1v = 0, i2v = 0;

  // ---- main loop: single 16KB w buffer, register prefetch, counted-wait barrier
  for (int ch = 0; ch < NCH; ++ch) {
    __syncthreads();                           // prev chunk's readers done (covers hoist at ch=0)
#pragma unroll
    for (int i = 0; i < 4; ++i)
      *(uint4*)(uni + (size_t)(i * BLK + tid) * 16) = G[i];
    if (ch + 1 < NCH) loadG(ch + 1);           // global loads stay in flight across raw barrier
    asm volatile("s_waitcnt lgkmcnt(0)" ::: "memory");
    __builtin_amdgcn_sched_barrier(0);         // rule #18: pin reads after the waitcnt
    __builtin_amdgcn_s_barrier();

    const _Float16* wb = (const _Float16*)uni;
#pragma unroll
    for (int et = 0; et < 4; ++et) {
      f16x8 ah[4];
#pragma unroll
      for (int kt = 0; kt < 4; ++kt)
        ah[kt] = *(const f16x8*)(wb + ((et * 4 + kt) * 64 + lane) * 8);
      f32x4 a = {0.f, 0.f, 0.f, 0.f};
#pragma unroll
      for (int kt = 0; kt < 4; ++kt) {
        a = __builtin_amdgcn_mfma_f32_16x16x32_f16(ah[kt], bh[kt], a, 0, 0, 0);
        a = __builtin_amdgcn_mfma_f32_16x16x32_f16(ah[kt], bl[kt], a, 0, 0, 0);
      }
      const int e0 = ch * ECH + et * 16 + g * 4;
      const float4 wn = *(const float4*)(ws->wnh + e0);
#pragma unroll
      for (int r = 0; r < 4; ++r) {
        float sc = ((const float*)&wn)[r] - a[r];
        ins3(sc, e0 + r, b1, b2, b3, i1v, i2v);
      }
    }
  }

  // ---- intra-wave butterfly over g (disjoint e-sets) -> lanes of same col hold merged top-3
#pragma unroll
  for (int sh = 0; sh < 2; ++sh) {
    const int off = 16 << sh;
    float p1 = __shfl_xor(b1, off), p2 = __shfl_xor(b2, off), p3 = __shfl_xor(b3, off);
    int q1 = __shfl_xor(i1v, off), q2 = __shfl_xor(i2v, off);
    ins3(p1, q1, b1, b2, b3, i1v, i2v);
    ins3(p2, q2, b1, b2, b3, i1v, i2v);
    ins3(p3, 0x7fffffff, b1, b2, b3, i1v, i2v);
  }

  // ---- tie handling, per wave (x~ from regs; fp64-on-x~ consistent across paths)
  {
    const bool t2 = (b2 - b1 < TIE_T);
    const bool t3 = (b3 - b1 < TIE_T);
    if (g == 0 && !t2 && !t3) { sIdx[wv * 16 + col] = i1v; atomicAdd(&hist[i1v], 1); }
    unsigned long long mask = __ballot(t2 || t3) & 0xFFFFull;
    float* scr = (float*)(uni + 16384 + wv * 512);
    while (mask) {
      const int bsel = __ffsll((unsigned long long)mask) - 1;
      mask &= mask - 1;
      if (col == bsel) {
#pragma unroll
        for (int kt = 0; kt < 4; ++kt)
#pragma unroll
          for (int j = 0; j < 8; ++j)
            scr[kt * 32 + g * 8 + j] = (float)bh[kt][j] + (float)bl[kt][j];
      }
      asm volatile("s_waitcnt lgkmcnt(0)" ::: "memory");
      __builtin_amdgcn_sched_barrier(0);       // rule #18
      const int j1s = __shfl(i1v, bsel), j2s = __shfl(i2v, bsel);
      const int isfull = __shfl((int)t3, bsel);
      int bi;
      if (isfull) {
        // candidate-parallel exact scan: 8 candidates per lane
        double bd = 1e300; int bj = 0x7fffffff;
        for (int i = 0; i < 8; ++i) {
          const int e = lane * 8 + i;
          const float* w = wt + (size_t)e * CDIM;
          double s = 0.0;
#pragma unroll 4
          for (int c = 0; c < CDIM; ++c) {
            double wd = (double)w[c];
            s = fma(wd, fma(0.5, wd, -(double)scr[c]), s);
          }
          if (s < bd || (s == bd && e < bj)) { bd = s; bj = e; }
        }
#pragma unroll
        for (int off = 32; off > 0; off >>= 1) {
          double od = __shfl_xor(bd, off); int oj = __shfl_xor(bj, off);
          if (od < bd || (od == bd && oj < bj)) { bd = od; bj = oj; }
        }
        bi = bj;
      } else {
        // 2-candidate parallel rescore: lanes<32 -> j1, lanes>=32 -> j2
        const int cand = (lane < 32) ? j1s : j2s;
        const int c0 = (lane & 31) * 4;
        const float* w = wt + (size_t)cand * CDIM;
        double p = 0.0;
#pragma unroll
        for (int cc = 0; cc < 4; ++cc) {
          double wd = (double)w[c0 + cc];
          p = fma(wd, fma(0.5, wd, -(double)scr[c0 + cc]), p);
        }
#pragma unroll
        for (int off = 16; off > 0; off >>= 1) p += __shfl_xor(p, off);
        double s1 = __shfl(p, 0), s2 = __shfl(p, 32);
        bi = (s2 < s1 || (s2 == s1 && j2s < j1s)) ? j2s : j1s;
      }
      if (lane == 0) { sIdx[wv * 16 + bsel] = bi; atomicAdd(&hist[bi], 1); }
    }
  }
  __syncthreads();

  // ---- loss from register x~ (no stores; q rows are L1/L2-resident)
  {
    const int m = wv * 16 + col;
    const int bi = sIdx[m];
    const float* wq = wt + (size_t)bi * CDIM;
    float ls = 0.f;
#pragma unroll
    for (int kt = 0; kt < 4; ++kt) {
      const int cb = kt * 32 + g * 8;
      float4 qa = *(const float4*)(wq + cb);
      float4 qb = *(const float4*)(wq + cb + 4);
      float qf[8] = {qa.x, qa.y, qa.z, qa.w, qb.x, qb.y, qb.z, qb.w};
#pragma unroll
      for (int j = 0; j < 8; ++j) {
        float xs = (float)bh[kt][j] + (float)bl[kt][j];
        float d = qf[j] - xs;
        ls = fmaf(d, d, ls);
      }
    }
#pragma unroll
    for (int off = 32; off > 0; off >>= 1) ls += __shfl_xor(ls, off);
    if (lane == 0) lredw[wv] = (double)ls;
  }

  // ---- out_q: coalesced r4 mapping — 64 consecutive vecs per store (256B contiguous)
  {
    const int vec = tid & (MT - 1);
    const int qd  = tid >> 6;               // 4 quarters of 32 channels
    const int bi  = sIdx[vec];
    const float* wq2 = wt + (size_t)bi * CDIM;
    const size_t gbase = ibase + s0 + vec;
#pragma unroll
    for (int cc = 0; cc < 32; cc += 4) {
      const int c = qd * 32 + cc;
      float4 qv = *(const float4*)(wq2 + c);
      __builtin_nontemporal_store(qv.x, out_q + gbase + (size_t)(c + 0) * SPATIAL);
      __builtin_nontemporal_store(qv.y, out_q + gbase + (size_t)(c + 1) * SPATIAL);
      __builtin_nontemporal_store(qv.z, out_q + gbase + (size_t)(c + 2) * SPATIAL);
      __builtin_nontemporal_store(qv.w, out_q + gbase + (size_t)(c + 3) * SPATIAL);
    }
  }
  __syncthreads();
  if (tid == 0) atomicAdd(&ws->lossAcc, lredw[0] + lredw[1] + lredw[2] + lredw[3]);

  // ---- encodings: 64 one-hot rows, 256 u64 columns (r2/r4-verified writer)
  {
    const size_t r0 = (size_t)blockIdx.x * MT;
    const int c0 = tid * 2;
    unsigned long long* e2 = (unsigned long long*)enc;
    for (int r = 0; r < MT; ++r) {
      int idx = sIdx[r];
      union { float2 f; unsigned long long u; } cvt;
      cvt.f.x = (idx == c0) ? 1.0f : 0.0f;
      cvt.f.y = (idx == c0 + 1) ? 1.0f : 0.0f;
      __builtin_nontemporal_store(cvt.u, e2 + (r0 + (size_t)r) * (EDIM / 2) + tid);
    }
  }

  for (int e = tid; e < EDIM; e += BLK) {
    int v = hist[e];
    if (v) atomicAdd(&ws->counts[e], v);
  }
}

// ---- finalize
__global__ __launch_bounds__(512) void vq_fin(const WS* __restrict__ ws, float* __restrict__ out) {
  __shared__ double red[EDIM];
  int t = threadIdx.x;
  double p = (double)ws->counts[t] * (1.0 / (double)NVEC);
  red[t] = p * log(p + 1e-10);
  __syncthreads();
  for (int off = 256; off > 0; off >>= 1) {
    if (t < off) red[t] += red[t + off];
    __syncthreads();
  }
  if (t == 0) {
    out[0] = (float)(1.25 * ws->lossAcc / (double)QELEMS);
    out[1 + QELEMS] = (float)exp(-red[0]);
  }
}

extern "C" void kernel_launch(void* const* d_in, const int* in_sizes, int n_in,
                              void* d_out, int out_size, void* d_ws, size_t ws_size,
                              hipStream_t stream) {
  const float* in = (const float*)d_in[0];
  const float* wt = (const float*)d_in[1];
  float* out = (float*)d_out;
  WS* ws = (WS*)d_ws;

  float* out_q = out + 1;
  float* enc   = out + 2 + QELEMS;

  const bool useWP = (ws_size >= sizeof(WS));
  vq_pre<<<dim3(64), dim3(256), 0, stream>>>(wt, ws, useWP ? 1 : 0);
  if (useWP)
    vq_main<true><<<dim3(NVEC / MT), dim3(BLK), 0, stream>>>(in, wt, ws, out_q, enc);
  else
    vq_main<false><<<dim3(NVEC / MT), dim3(BLK), 0, stream>>>(in, wt, ws, out_q, enc);
  vq_fin<<<dim3(1), dim3(512), 0, stream>>>(ws, out);
}